// Round 4
// baseline (305.252 us; speedup 1.0000x reference)
//
#include <hip/hip_runtime.h>

namespace {

constexpr float FF[12] = {0.0144f, 0.0272f, 0.0526f, 0.0972f, 0.193f, 0.63f,
                          -0.63f, -0.193f, -0.0972f, -0.0526f, -0.0272f, -0.0144f};
constexpr float SQ2   = 1.41421356237309515f;
constexpr float NISQ2 = -0.70710678118654752f;

// Horizontal 12-tap correlation on one LDS row (float4-grouped), periodic width W4*4.
template <int O, int W4>
__device__ __forceinline__ float4 hconv(const float4* R4, int row4, int j4) {
  float r[20];
#pragma unroll
  for (int d = 0; d < 5; ++d) {
    float4 t = R4[row4 + ((j4 + d - 2) & (W4 - 1))];
    r[4 * d + 0] = t.x; r[4 * d + 1] = t.y; r[4 * d + 2] = t.z; r[4 * d + 3] = t.w;
  }
  float4 o = make_float4(0.f, 0.f, 0.f, 0.f);
#pragma unroll
  for (int a = 0; a < 12; ++a) {
    const float fa = FF[a];
    o.x += fa * r[8 + 0 + a - O];
    o.y += fa * r[8 + 1 + a - O];
    o.z += fa * r[8 + 2 + a - O];
    o.w += fa * r[8 + 3 + a - O];
  }
  return o;
}

// Vertical 12-tap correlation, plain periodic rows (stage 1: 128 rows x 32 groups).
template <int O>
__device__ __forceinline__ float4 vconv_s1(const float4* S4, int i, int j4) {
  float4 o = make_float4(0.f, 0.f, 0.f, 0.f);
#pragma unroll
  for (int a = 0; a < 12; ++a) {
    const float fa = FF[a];
    float4 v = S4[((i + a - O) & 127) * 32 + j4];
    o.x += fa * v.x; o.y += fa * v.y; o.z += fa * v.z; o.w += fa * v.w;
  }
  return o;
}

// Vertical 12-tap correlation, qper_col rows (stage 2: 128 rows x 64 groups;
// out-of-range rows wrap with column+128 shift == group XOR 32).
template <int O>
__device__ __forceinline__ float4 vconv_s2(const float4* S4, int i, int j4) {
  float4 o = make_float4(0.f, 0.f, 0.f, 0.f);
#pragma unroll
  for (int a = 0; a < 12; ++a) {
    const float fa = FF[a];
    int r = i + a - O;
    int idx = ((unsigned)r < 128u) ? (r * 64 + j4) : ((r & 127) * 64 + (j4 ^ 32));
    float4 v = S4[idx];
    o.x += fa * v.x; o.y += fa * v.y; o.z += fa * v.z; o.w += fa * v.w;
  }
  return o;
}

// qprec '2c' scalar gather: x[i,jo] from p0 (bufB) / p1 (bufA), both 128x128.
__device__ __forceinline__ float qp2c(const float* __restrict__ bufA,
                                      const float* __restrict__ bufB,
                                      int i, int jo) {
  int J = (i + jo) & 255;
  int c = J >> 1;
  return (J & 1) ? bufA[((i - 1 - c) & 127) * 128 + c]
                 : bufB[((i - c) & 127) * 128 + c];
}

// stage-2 even-I output gather from p0 (buf, 128x256).
__device__ __forceinline__ float pp0(const float* __restrict__ buf, int i, int jo) {
  int r = ((i + jo) & 255) >> 1;
  return buf[r * 256 + ((jo - r) & 255)];
}

// Named 8x float4 — NOT an array, so no alloca can be demoted to scratch.
struct F4x8 { float4 v0, v1, v2, v3, v4, v5, v6, v7; };

#define FOR4(M) M(0) M(1) M(2) M(3)
#define FOR8(M) M(0) M(1) M(2) M(3) M(4) M(5) M(6) M(7)
#define FOR16(M) FOR8(M) M(8) M(9) M(10) M(11) M(12) M(13) M(14) M(15)

// Stage-1 plane: fbrec(Y0, Y1, '2c', 'per') for one 128x128 channel pair.
// Result x-plane (128x256 fp32) is left in named members xv.vK, member K
// holding float4 group t = tid + K*1024 (the layout stage-2 consumes).
__device__ __forceinline__ void s1_plane(const float4* __restrict__ Y04,
                                         const float4* __restrict__ Y14,
                                         float* __restrict__ bufA,
                                         float* __restrict__ bufB,
                                         F4x8& xv, int tid) {
  float4* A4 = reinterpret_cast<float4*>(bufA);
  float4* B4 = reinterpret_cast<float4*>(bufB);

  // 1. load Y0 plane -> A
#define S1L(K) A4[tid + K * 1024] = Y04[tid + K * 1024];
  FOR4(S1L)
#undef S1L
  __syncthreads();

  // 2. B = vert conv offset-5 of Y0
#define S1V5(K) { int g = tid + K * 1024; B4[g] = vconv_s1<5>(A4, g >> 5, g & 31); }
  FOR4(S1V5)
#undef S1V5
  __syncthreads();

  // 3. A = p1 = -1/sqrt2 * (Y1 + horz conv offset-5 of B)
#define S1P1(K) { int g = tid + K * 1024; int i = g >> 5, j4 = g & 31;             \
    float4 h = hconv<5, 32>(B4, i * 32, j4); float4 yv = Y14[g];                   \
    A4[g] = make_float4(NISQ2 * (yv.x + h.x), NISQ2 * (yv.y + h.y),                \
                        NISQ2 * (yv.z + h.z), NISQ2 * (yv.w + h.w)); }
  FOR4(S1P1)
#undef S1P1
  __syncthreads();

  // 4. B = vert conv offset-6 of p1
#define S1V6(K) { int g = tid + K * 1024; B4[g] = vconv_s1<6>(A4, g >> 5, g & 31); }
  FOR4(S1V6)
#undef S1V6
  __syncthreads();

  // 5. B = p0 = sqrt2*Y0 + horz conv offset-6 of B (named-reg staged; Y0 from L2)
  float4 pv0, pv1, pv2, pv3;
#define S1P0(K) { int g = tid + K * 1024; int i = g >> 5, j4 = g & 31;             \
    float4 h = hconv<6, 32>(B4, i * 32, j4); float4 yv = Y04[g];                   \
    pv##K = make_float4(SQ2 * yv.x + h.x, SQ2 * yv.y + h.y,                        \
                        SQ2 * yv.z + h.z, SQ2 * yv.w + h.w); }
  FOR4(S1P0)
#undef S1P0
  __syncthreads();
#define S1W(K) B4[tid + K * 1024] = pv##K;
  FOR4(S1W)
#undef S1W
  __syncthreads();

  // 6. qprec '2c' permute -> named registers.
#define S1Q(K) { int tt = tid + K * 1024; int i = tt >> 6; int jb = (tt & 63) << 2; \
    xv.v##K = make_float4(qp2c(bufA, bufB, i, jb + 0), qp2c(bufA, bufB, i, jb + 1), \
                          qp2c(bufA, bufB, i, jb + 2), qp2c(bufA, bufB, i, jb + 3)); }
  FOR8(S1Q)
#undef S1Q
  __syncthreads();  // permute reads done; LDS free for reuse
}

}  // namespace

// Fully fused: one block per output plane (b,c).  Stage-1 runs twice with
// results carried in NAMED registers (struct members / named scalars — no
// arrays, so nothing can be alloca-demoted to scratch); stage-2 consumes them
// without any HBM intermediate; output written as merged coalesced float4.
// amdgpu_waves_per_eu(4,4): LDS (128 KiB) caps at one resident 1024-thread
// block = 4 waves/EU; pin regalloc to that -> 128-VGPR budget.
__global__ __launch_bounds__(1024)
__attribute__((amdgpu_waves_per_eu(4, 4)))
void fused_kernel(
    const float* __restrict__ y0, const float* __restrict__ y1,
    const float* __restrict__ y2, const float* __restrict__ y3,
    float* __restrict__ out) {
  __shared__ float buf[32768];  // union: s1 {A,B} 64KiB each | s2 plane 128KiB
  float* bufA = buf;
  float* bufB = buf + 16384;
  float4* X4 = reinterpret_cast<float4*>(buf);

  const int q = blockIdx.x;  // 0..255 = b*32 + c
  const int tid = threadIdx.x;
  const size_t sub4 = (size_t)q * 4096;  // input plane offset in float4

  const float4* Y0a = reinterpret_cast<const float4*>(y2) + sub4;  // x1 inputs
  const float4* Y1a = reinterpret_cast<const float4*>(y3) + sub4;
  const float4* Y0b = reinterpret_cast<const float4*>(y1) + sub4;  // x0 inputs
  const float4* Y1b = reinterpret_cast<const float4*>(y0) + sub4;

  F4x8 xv1, xv0;
  s1_plane(Y0a, Y1a, bufA, bufB, xv1, tid);  // x1 = x[:, 32+c]
  s1_plane(Y0b, Y1b, bufA, bufB, xv0, tid);  // x0 = x[:, c]

  // ---------------- stage 2: fbrec(x0, x1, '1r', 'qper_col') ----------------
  // 1. x0 -> LDS
#define S21(K) X4[tid + K * 1024] = xv0.v##K;
  FOR8(S21)
#undef S21
  __syncthreads();

  // 2. vert conv offset-5 (qper rows), named-reg staged, in-place
  float4 t0, t1, t2, t3, t4, t5, t6, t7;
#define S22(K) { int g = tid + K * 1024; t##K = vconv_s2<5>(X4, g >> 6, g & 63); }
  FOR8(S22)
#undef S22
  __syncthreads();
#define S22W(K) X4[tid + K * 1024] = t##K;
  FOR8(S22W)
#undef S22W
  __syncthreads();

  // 3. p1 = -1/sqrt2 * (x1 + horz conv offset-5); overwrites xv1 members
#define S23(K) { int g = tid + K * 1024; int i = g >> 6, j4 = g & 63;              \
    float4 h = hconv<5, 64>(X4, i * 64, j4);                                       \
    xv1.v##K = make_float4(NISQ2 * (xv1.v##K.x + h.x), NISQ2 * (xv1.v##K.y + h.y), \
                           NISQ2 * (xv1.v##K.z + h.z), NISQ2 * (xv1.v##K.w + h.w)); }
  FOR8(S23)
#undef S23
  __syncthreads();
#define S23W(K) X4[tid + K * 1024] = xv1.v##K;
  FOR8(S23W)
#undef S23W
  __syncthreads();

  // 3b. stash odd-I output values (permute of p1) in NAMED scalars.
  //     out[i,jo] = p1[r, (jo-1-r)&255], r=((i+jo)&255)>>1; odd slots at
  //     m = m0, m0+2 with m0 = 1-(i&1).
#define DECLOV(K) float ov_##K##_0, ov_##K##_1;
  FOR16(DECLOV)
#undef DECLOV
#define S3B(K) { int tt = tid + K * 1024; int i = tt >> 6; int jb = (tt & 63) << 2; \
    int m0 = 1 - (i & 1);                                                           \
    { int jo = jb + m0;     int r = ((i + jo) & 255) >> 1;                          \
      ov_##K##_0 = buf[r * 256 + ((jo - 1 - r) & 255)]; }                           \
    { int jo = jb + m0 + 2; int r = ((i + jo) & 255) >> 1;                          \
      ov_##K##_1 = buf[r * 256 + ((jo - 1 - r) & 255)]; } }
  FOR16(S3B)
#undef S3B
  // (reads only; ordered vs. the next overwrite by the sync after step-4 compute)

  // 4. vert conv offset-6 of p1 (qper rows), named-reg staged, in-place
#define S24(K) { int g = tid + K * 1024; t##K = vconv_s2<6>(X4, g >> 6, g & 63); }
  FOR8(S24)
#undef S24
  __syncthreads();
#define S24W(K) X4[tid + K * 1024] = t##K;
  FOR8(S24W)
#undef S24W
  __syncthreads();

  // 5. p0 = sqrt2*x0 + horz conv offset-6; overwrites xv0 members
#define S25(K) { int g = tid + K * 1024; int i = g >> 6, j4 = g & 63;              \
    float4 h = hconv<6, 64>(X4, i * 64, j4);                                       \
    xv0.v##K = make_float4(SQ2 * xv0.v##K.x + h.x, SQ2 * xv0.v##K.y + h.y,         \
                           SQ2 * xv0.v##K.z + h.z, SQ2 * xv0.v##K.w + h.w); }
  FOR8(S25)
#undef S25
  __syncthreads();
#define S25W(K) X4[tid + K * 1024] = xv0.v##K;
  FOR8(S25W)
#undef S25W
  __syncthreads();

  // 6. merged, fully-coalesced write: even-I from p0 (LDS), odd-I from ov regs.
  float4* op4 = reinterpret_cast<float4*>(out) + (size_t)q * 16384;
#define S26(K) { int tt = tid + K * 1024; int i = tt >> 6; int jb = (tt & 63) << 2; \
    float4 v;                                                                       \
    if (i & 1) { v.x = ov_##K##_0;        v.y = pp0(buf, i, jb + 1);                \
                 v.z = ov_##K##_1;        v.w = pp0(buf, i, jb + 3); }              \
    else       { v.x = pp0(buf, i, jb);   v.y = ov_##K##_0;                         \
                 v.z = pp0(buf, i, jb + 2); v.w = ov_##K##_1; }                     \
    op4[tt] = v; }
  FOR16(S26)
#undef S26
}

extern "C" void kernel_launch(void* const* d_in, const int* in_sizes, int n_in,
                              void* d_out, int out_size, void* d_ws, size_t ws_size,
                              hipStream_t stream) {
  const float* y0 = (const float*)d_in[0];
  const float* y1 = (const float*)d_in[1];
  const float* y2 = (const float*)d_in[2];
  const float* y3 = (const float*)d_in[3];
  float* outp = (float*)d_out;
  (void)d_ws; (void)ws_size;  // no HBM intermediate

  fused_kernel<<<256, 1024, 0, stream>>>(y0, y1, y2, y3, outp);
}

// Round 5
// 196.271 us; speedup vs baseline: 1.5553x; 1.5553x over previous
//
#include <hip/hip_runtime.h>

namespace {

constexpr float FF[12] = {0.0144f, 0.0272f, 0.0526f, 0.0972f, 0.193f, 0.63f,
                          -0.63f, -0.193f, -0.0972f, -0.0526f, -0.0272f, -0.0144f};
constexpr float SQ2   = 1.41421356237309515f;
constexpr float NISQ2 = -0.70710678118654752f;

// Horizontal 12-tap correlation on one LDS row (float4-grouped), periodic width W4*4.
template <int O, int W4>
__device__ __forceinline__ float4 hconv(const float4* R4, int row4, int j4) {
  float r[20];
#pragma unroll
  for (int d = 0; d < 5; ++d) {
    float4 t = R4[row4 + ((j4 + d - 2) & (W4 - 1))];
    r[4 * d + 0] = t.x; r[4 * d + 1] = t.y; r[4 * d + 2] = t.z; r[4 * d + 3] = t.w;
  }
  float4 o = make_float4(0.f, 0.f, 0.f, 0.f);
#pragma unroll
  for (int a = 0; a < 12; ++a) {
    const float fa = FF[a];
    o.x += fa * r[8 + 0 + a - O];
    o.y += fa * r[8 + 1 + a - O];
    o.z += fa * r[8 + 2 + a - O];
    o.w += fa * r[8 + 3 + a - O];
  }
  return o;
}

// Vertical 12-tap correlation, plain periodic rows (stage 1: 128 rows x 32 groups).
template <int O>
__device__ __forceinline__ float4 vconv_s1(const float4* S4, int i, int j4) {
  float4 o = make_float4(0.f, 0.f, 0.f, 0.f);
#pragma unroll
  for (int a = 0; a < 12; ++a) {
    const float fa = FF[a];
    float4 v = S4[((i + a - O) & 127) * 32 + j4];
    o.x += fa * v.x; o.y += fa * v.y; o.z += fa * v.z; o.w += fa * v.w;
  }
  return o;
}

// Vertical 12-tap correlation, qper_col rows (stage 2: 128 rows x 64 groups;
// out-of-range rows wrap with column+128 shift == group XOR 32).
template <int O>
__device__ __forceinline__ float4 vconv_s2(const float4* S4, int i, int j4) {
  float4 o = make_float4(0.f, 0.f, 0.f, 0.f);
#pragma unroll
  for (int a = 0; a < 12; ++a) {
    const float fa = FF[a];
    int r = i + a - O;
    int idx = ((unsigned)r < 128u) ? (r * 64 + j4) : ((r & 127) * 64 + (j4 ^ 32));
    float4 v = S4[idx];
    o.x += fa * v.x; o.y += fa * v.y; o.z += fa * v.z; o.w += fa * v.w;
  }
  return o;
}

// qprec '2c' scalar gather: x[i,jo] from p1 (bufA) / p0 (bufB), both 128x128.
__device__ __forceinline__ float qp2c(const float* __restrict__ bufA,
                                      const float* __restrict__ bufB,
                                      int i, int jo) {
  int J = (i + jo) & 255;
  int c = J >> 1;
  return (J & 1) ? bufA[((i - 1 - c) & 127) * 128 + c]
                 : bufB[((i - c) & 127) * 128 + c];
}

// Stage-1 core: fbrec filter chain for one 128x128 channel pair.
// On exit: A = p1, B = p0 (both 128x128), with a trailing barrier.
// Live register state: pv[4] only (16 floats) — fits the 64-VGPR cap.
__device__ __forceinline__ void s1_core(const float4* __restrict__ Y04,
                                        const float4* __restrict__ Y14,
                                        float4* __restrict__ A4,
                                        float4* __restrict__ B4, int tid) {
  // 1. load Y0 plane -> A
#pragma unroll
  for (int k = 0; k < 4; ++k) A4[tid + k * 1024] = Y04[tid + k * 1024];
  __syncthreads();

  // 2. B = vert conv offset-5 of Y0
#pragma unroll
  for (int k = 0; k < 4; ++k) {
    int g = tid + k * 1024;
    B4[g] = vconv_s1<5>(A4, g >> 5, g & 31);
  }
  __syncthreads();

  // 3. A = p1 = -1/sqrt2 * (Y1 + horz conv offset-5 of B)
#pragma unroll
  for (int k = 0; k < 4; ++k) {
    int g = tid + k * 1024;
    int i = g >> 5, j4 = g & 31;
    float4 h = hconv<5, 32>(B4, i * 32, j4);
    float4 yv = Y14[g];
    A4[g] = make_float4(NISQ2 * (yv.x + h.x), NISQ2 * (yv.y + h.y),
                        NISQ2 * (yv.z + h.z), NISQ2 * (yv.w + h.w));
  }
  __syncthreads();

  // 4. B = vert conv offset-6 of p1
#pragma unroll
  for (int k = 0; k < 4; ++k) {
    int g = tid + k * 1024;
    B4[g] = vconv_s1<6>(A4, g >> 5, g & 31);
  }
  __syncthreads();

  // 5. B = p0 = sqrt2*Y0 + horz conv offset-6 of B (reg-staged; Y0 reloaded from L2)
  float4 pv[4];
#pragma unroll
  for (int k = 0; k < 4; ++k) {
    int g = tid + k * 1024;
    int i = g >> 5, j4 = g & 31;
    float4 h = hconv<6, 32>(B4, i * 32, j4);
    float4 yv = Y04[g];
    pv[k] = make_float4(SQ2 * yv.x + h.x, SQ2 * yv.y + h.y,
                        SQ2 * yv.z + h.z, SQ2 * yv.w + h.w);
  }
  __syncthreads();
#pragma unroll
  for (int k = 0; k < 4; ++k) B4[tid + k * 1024] = pv[k];
  __syncthreads();
}

}  // namespace

// Fused, 64-VGPR-honest: one block per output plane (b,c).  All large
// cross-phase state rides the HBM workspace via SAME-LANE write->read round
// trips (each thread re-reads exactly the addresses it wrote => no coherence
// hazard, and reads are L2-local on the same XCD).  Max register live set is
// 32 floats (tv/g8), matching the round-0 kernels that ran scratch-free at
// the toolchain's hard 64-VGPR cap (rounds 1-4: every >40-float design was
// demoted to scratch; ~225-300 MB of spill traffic, immune to launch_bounds
// and waves_per_eu).  Output uses split scalar writes (odd-I while p1 is in
// LDS, even-I from p0): 2x write amp ~ 13 us, far cheaper than scratch.
__global__ __launch_bounds__(1024) void fused_kernel(
    const float* __restrict__ y0, const float* __restrict__ y1,
    const float* __restrict__ y2, const float* __restrict__ y3,
    float* __restrict__ out, float* __restrict__ ws) {
  __shared__ float buf[32768];  // union: s1 {A,B} 64KiB each | s2 plane 128KiB
  float* bufA = buf;
  float* bufB = buf + 16384;
  float4* A4 = reinterpret_cast<float4*>(bufA);
  float4* B4 = reinterpret_cast<float4*>(bufB);
  float4* X4 = reinterpret_cast<float4*>(buf);

  const int q = blockIdx.x;  // 0..255 = b*32 + c
  const int tid = threadIdx.x;
  const size_t sub4 = (size_t)q * 4096;  // input plane offset in float4

  const float4* Y0a = reinterpret_cast<const float4*>(y2) + sub4;  // x1 inputs
  const float4* Y1a = reinterpret_cast<const float4*>(y3) + sub4;
  const float4* Y0b = reinterpret_cast<const float4*>(y1) + sub4;  // x0 inputs
  const float4* Y1b = reinterpret_cast<const float4*>(y0) + sub4;

  // Per-block ws slot: 65536 floats (x0 plane then x1 plane, 128 KiB each).
  float4* wsX0 = reinterpret_cast<float4*>(ws) + (size_t)q * 16384;
  float4* wsX1 = wsX0 + 8192;

  // ---------------- part A: x1 = fbrec(y2,y3) -> ws ----------------
  s1_core(Y0a, Y1a, A4, B4, tid);
  // qprec '2c' permute, gathered from LDS, written coalesced to ws.
#pragma unroll
  for (int k = 0; k < 8; ++k) {
    int t = tid + k * 1024;
    int i = t >> 6;
    int jb = (t & 63) << 2;
    float tmp[4];
#pragma unroll
    for (int m = 0; m < 4; ++m) tmp[m] = qp2c(bufA, bufB, i, jb + m);
    wsX1[t] = make_float4(tmp[0], tmp[1], tmp[2], tmp[3]);
  }
  __syncthreads();  // permute LDS reads done before part B overwrites A/B

  // ---------------- part B: x0 = fbrec(y1,y0) -> LDS plane + ws ----------------
  s1_core(Y0b, Y1b, A4, B4, tid);
  float4 g8[8];
#pragma unroll
  for (int k = 0; k < 8; ++k) {
    int t = tid + k * 1024;
    int i = t >> 6;
    int jb = (t & 63) << 2;
    float tmp[4];
#pragma unroll
    for (int m = 0; m < 4; ++m) tmp[m] = qp2c(bufA, bufB, i, jb + m);
    g8[k] = make_float4(tmp[0], tmp[1], tmp[2], tmp[3]);
  }
  __syncthreads();  // gather reads done; safe to overwrite the union buffer
#pragma unroll
  for (int k = 0; k < 8; ++k) {
    int t = tid + k * 1024;
    X4[t] = g8[k];     // stage-2 phase-1 content, no ws read needed
    wsX0[t] = g8[k];   // parked copy for the phase-5 re-read (same lane)
  }
  __syncthreads();

  // ---------------- stage 2: fbrec(x0, x1, '1r', 'qper_col') ----------------
  float* op = out + (size_t)q * 65536;
  float4 tv[8];

  // 2. vert conv offset-5 (qper rows), reg-staged in-place
#pragma unroll
  for (int k = 0; k < 8; ++k) {
    int g = tid + k * 1024;
    tv[k] = vconv_s2<5>(X4, g >> 6, g & 63);
  }
  __syncthreads();
#pragma unroll
  for (int k = 0; k < 8; ++k) X4[tid + k * 1024] = tv[k];
  __syncthreads();

  // 3. p1 = -1/sqrt2 * (x1 + horz conv offset-5); x1 streamed from ws
  //    (same-lane re-read of part A's writes -> L2-local)
#pragma unroll
  for (int k = 0; k < 8; ++k) {
    int g = tid + k * 1024;
    int i = g >> 6, j4 = g & 63;
    float4 h = hconv<5, 64>(X4, i * 64, j4);
    float4 xv = wsX1[g];
    tv[k] = make_float4(NISQ2 * (xv.x + h.x), NISQ2 * (xv.y + h.y),
                        NISQ2 * (xv.z + h.z), NISQ2 * (xv.w + h.w));
  }
  __syncthreads();
#pragma unroll
  for (int k = 0; k < 8; ++k) X4[tid + k * 1024] = tv[k];
  __syncthreads();

  // 3b. odd-I outputs while buf == p1: out[i,jo] = p1[r, (jo-1-r)&255],
  //     I=(i+jo)&255 odd, r=I>>1.  Scalar stride-2 stores (reads only; the
  //     sync after step-4 compute orders these vs. the next buf overwrite).
#pragma unroll
  for (int k = 0; k < 32; ++k) {
    int t = tid + k * 1024;  // 32768 odd positions
    int i = t >> 7;
    int u = t & 127;
    int jo = (u << 1) | ((i + 1) & 1);
    int r = ((i + jo) & 255) >> 1;
    int cc2 = (jo - 1 - r) & 255;
    op[i * 256 + jo] = buf[r * 256 + cc2];
  }

  // 4. vert conv offset-6 of p1 (qper rows), reg-staged in-place
#pragma unroll
  for (int k = 0; k < 8; ++k) {
    int g = tid + k * 1024;
    tv[k] = vconv_s2<6>(X4, g >> 6, g & 63);
  }
  __syncthreads();
#pragma unroll
  for (int k = 0; k < 8; ++k) X4[tid + k * 1024] = tv[k];
  __syncthreads();

  // 5. p0 = sqrt2*x0 + horz conv offset-6; x0 re-read from ws (same lane,
  //    written ~3 phases ago on this XCD -> mostly L2)
#pragma unroll
  for (int k = 0; k < 8; ++k) {
    int g = tid + k * 1024;
    int i = g >> 6, j4 = g & 63;
    float4 h = hconv<6, 64>(X4, i * 64, j4);
    float4 xv = wsX0[g];
    tv[k] = make_float4(SQ2 * xv.x + h.x, SQ2 * xv.y + h.y,
                        SQ2 * xv.z + h.z, SQ2 * xv.w + h.w);
  }
  __syncthreads();
#pragma unroll
  for (int k = 0; k < 8; ++k) X4[tid + k * 1024] = tv[k];
  __syncthreads();

  // 6. even-I outputs: out[i,jo] = p0[r, (jo-r)&255], I even, r=I>>1.
#pragma unroll
  for (int k = 0; k < 32; ++k) {
    int t = tid + k * 1024;
    int i = t >> 7;
    int u = t & 127;
    int jo = (u << 1) | (i & 1);
    int r = ((i + jo) & 255) >> 1;
    int cc2 = (jo - r) & 255;
    op[i * 256 + jo] = buf[r * 256 + cc2];
  }
}

extern "C" void kernel_launch(void* const* d_in, const int* in_sizes, int n_in,
                              void* d_out, int out_size, void* d_ws, size_t ws_size,
                              hipStream_t stream) {
  const float* y0 = (const float*)d_in[0];
  const float* y1 = (const float*)d_in[1];
  const float* y2 = (const float*)d_in[2];
  const float* y3 = (const float*)d_in[3];
  float* outp = (float*)d_out;
  float* ws = (float*)d_ws;  // 64 MiB: per-block x0/x1 parking (same-lane round trips)

  fused_kernel<<<256, 1024, 0, stream>>>(y0, y1, y2, y3, outp, ws);
}